// Round 13
// baseline (343.832 us; speedup 1.0000x reference)
//
#include <hip/hip_runtime.h>
#include <hip/hip_bf16.h>

// Fused SE(3) feedforward, bf16 MFMA, fp32 accumulate.
// Round 13: R7 base (best, 232us) + nonlin write conflict fix:
//  (1) shfl_xor pair-pack -> even lanes write b32 (kills same-dword 2-way),
//  (2) lH swizzle ^((t&8)<<1) (kills g/g+2 bank-image 2-way), applied to both
//      nonlin writes and GEMM2 reads (both-sides-or-neither).
// Everything else byte-identical to R7.

typedef __attribute__((ext_vector_type(8))) short short8;   // 8 bf16 (MFMA A/B frag)
typedef __attribute__((ext_vector_type(4))) float f32x4;    // MFMA C/D frag

static __device__ __forceinline__ short f2bf(float f) {
  __hip_bfloat16 h = __float2bfloat16(f);
  return *reinterpret_cast<short*>(&h);
}
static __device__ __forceinline__ unsigned short u16bf(float f) {
  __hip_bfloat16 h = __float2bfloat16(f);
  return *reinterpret_cast<unsigned short*>(&h);
}

// ---- fused weight packing into MFMA-fragment order (bf16) ----
// region r = blockIdx.x>>7: r=2*dg+0 -> w_in(dg), r=2*dg+1 -> w_out(dg).
__global__ void pack_all_k(const float* __restrict__ w0i, const float* __restrict__ w0o,
                           const float* __restrict__ w1i, const float* __restrict__ w1o,
                           const float* __restrict__ w2i, const float* __restrict__ w2o,
                           short* __restrict__ p) {
  const int region = blockIdx.x >> 7;                 // 0..5
  const int gid = (blockIdx.x & 127) * 256 + threadIdx.x;  // 0..32767
  const int lane = gid & 63;
  const int tile = gid >> 6;
  const int gg = lane >> 4, cc = lane & 15;
  const float* w = (region == 0) ? w0i : (region == 1) ? w0o :
                   (region == 2) ? w1i : (region == 3) ? w1o :
                   (region == 4) ? w2i : w2o;
  short8 v;
  if (region & 1) {   // w_out pack: tile (kt2<32, nt2<16)
    const int nt2 = tile & 15, kt2 = tile >> 4;
#pragma unroll
    for (int j = 0; j < 8; ++j)
      v[j] = f2bf(w[(kt2 * 32 + gg * 8 + j) * 256 + nt2 * 16 + cc]);
  } else {            // w_in pack: tile (nt<64, kt<8)
    const int kt = tile & 7, nt = tile >> 3;
#pragma unroll
    for (int j = 0; j < 8; ++j)
      v[j] = f2bf(w[(kt * 32 + gg * 8 + j) * 1024 + nt * 16 + cc]);
  }
  *reinterpret_cast<short8*>(p + ((size_t)region * 262144) + gid * 8) = v;
}

// ---- fused main kernel (8 waves) ----
// NT token tiles of 16; tokens t = a*16 + r. GRP = norm-group size over tiles
// (GRP==NT for deg>0 where a=mm; GRP==1 for deg0 at 32 rows).
// lA swizzle: byte ^= (t&7)<<4.  lH swizzle: byte ^= ((t&7)<<4) ^ ((t&8)<<1).
template<int NT, int GRP, int OUT_M>
__global__ __launch_bounds__(512, 4)
void ff_se3_kernel(const float* __restrict__ x,
                   const short* __restrict__ wpin,
                   const short* __restrict__ wpout,
                   const float* __restrict__ scale,
                   const float* __restrict__ bias,
                   float* __restrict__ out)
{
  constexpr int T = 16 * NT;                  // tokens per block
  constexpr int R = (OUT_M == 1) ? T : 16;    // output rows per block
  extern __shared__ short lds[];              // T*512 (lA) + 2*T*256 (lH dbuf) bytes
  short* lA  = lds;
  short* lH0 = lds + T * 256;
  short* lH1 = lH0 + T * 128;

  const int tid  = threadIdx.x;
  const int lane = tid & 63;
  const int wave = tid >> 6;                  // 0..7
  const int g    = lane >> 4;
  const int lc   = lane & 15;
  const long row0 = (long)blockIdx.x * R;

  // stage x -> lA (nt float4 reads, scatter bf16 into token layout)
  for (int e4 = tid; e4 < R * 64 * OUT_M; e4 += 512) {
    const int r  = e4 / (64 * OUT_M);
    const int o4 = e4 - r * (64 * OUT_M);
    const f32x4 v = __builtin_nontemporal_load(
        reinterpret_cast<const f32x4*>(x + (row0 + r) * (256 * OUT_M) + o4 * 4));
#pragma unroll
    for (int i = 0; i < 4; ++i) {
      const int flat = o4 * 4 + i;
      const int d  = flat / OUT_M;
      const int mm = flat - d * OUT_M;
      const int t  = mm * 16 + r;             // deg0: mm=0 -> t=r
      const int byte = t * 512 + ((d * 2) ^ ((t & 7) << 4));
      lA[byte >> 1] = f2bf(v[i]);
    }
  }

  f32x4 acc_out[NT][2];                       // wave owns 32 d-cols (2 n-tiles)
#pragma unroll
  for (int a = 0; a < NT; ++a) { acc_out[a][0] = (f32x4)(0.f); acc_out[a][1] = (f32x4)(0.f); }

  __syncthreads();

  for (int c = 0; c < 8; ++c) {   // 128-h chunks
    short* lH = (c & 1) ? lH1 : lH0;

    // scale/bias prefetch (hidden under GEMM1); wave owns cols [wave*16, +16)
    const int hgl = c * 128 + wave * 16 + lc;
    const float sc = scale[hgl];
    const float bi = bias[hgl];

    // ---- GEMM1: wave owns 16 h-cols (1 n-tile), K=256 ----
    f32x4 acc1[NT];
#pragma unroll
    for (int a = 0; a < NT; ++a) acc1[a] = (f32x4)(0.f);
#pragma unroll
    for (int kt = 0; kt < 8; ++kt) {
      short8 af[NT];
#pragma unroll
      for (int a = 0; a < NT; ++a) {
        const int t = a * 16 + lc;
        const int byte = t * 512 + (((kt * 32 + g * 8) * 2) ^ ((t & 7) << 4));
        af[a] = *reinterpret_cast<const short8*>(&lA[byte >> 1]);
      }
      const int ntg = c * 8 + wave;
      const short8 bfr = *reinterpret_cast<const short8*>(wpin + ((ntg * 8 + kt) * 64 + lane) * 8);
#pragma unroll
      for (int a = 0; a < NT; ++a)
        acc1[a] = __builtin_amdgcn_mfma_f32_16x16x32_bf16(af[a], bfr, acc1[a], 0, 0, 0);
    }

    // ---- prefetch GEMM2 B-frags (in flight across nonlin + barrier) ----
    short8 b2p[4][2];
#pragma unroll
    for (int kk = 0; kk < 4; ++kk)
#pragma unroll
      for (int nn = 0; nn < 2; ++nn) {
        const int tile = (c * 4 + kk) * 16 + wave * 2 + nn;
        b2p[kk][nn] = *reinterpret_cast<const short8*>(wpout + (tile * 64 + lane) * 8);
      }

    // ---- nonlinearity: per-(row,h) norm over its GRP tiles + gelu gate ----
    // writes pair-packed b32 from even lanes (cols col, col+1)
#pragma unroll
    for (int reg = 0; reg < 4; ++reg) {
#pragma unroll
      for (int gi = 0; gi < NT / GRP; ++gi) {
        float ns = 0.f;
#pragma unroll
        for (int k = 0; k < GRP; ++k) {
          const float h = acc1[gi * GRP + k][reg];
          ns += h * h;
        }
        ns = fmaxf(ns, 1e-24f);
        const float rn  = __builtin_amdgcn_rsqf(ns);
        const float nrm = ns * rn;
        const float z   = fmaf(nrm, sc, bi);
        float u2 = 2.f * z * fmaf(0.0356774081f * z, z, 0.7978845608f);
        u2 = fminf(u2, 30.f);
        const float e  = __expf(u2);
        const float th = (e - 1.f) * __builtin_amdgcn_rcpf(e + 1.f);
        const float fac = 0.5f * (1.f + th) * z * rn;
        const int tl  = g * 4 + reg;
        const int col = wave * 16 + lc;         // even-lane col is even
#pragma unroll
        for (int k = 0; k < GRP; ++k) {
          const int a = gi * GRP + k;
          const int t = a * 16 + tl;
          const float v  = acc1[a][reg] * fac;
          const float vp = __shfl_xor(v, 1);    // partner col^1's value
          if ((lc & 1) == 0) {
            const unsigned pk = (unsigned)u16bf(v) | ((unsigned)u16bf(vp) << 16);
            const int byte = t * 256 + ((col * 2) ^ ((t & 7) << 4) ^ ((t & 8) << 1));
            *reinterpret_cast<unsigned*>(reinterpret_cast<char*>(lH) + byte) = pk;
          }
        }
      }
    }

    __syncthreads();   // the ONLY barrier per chunk

    // ---- GEMM2 partial: wave owns d-cols [wave*32, +32) ----
#pragma unroll
    for (int kk = 0; kk < 4; ++kk) {
      short8 a2[NT];
#pragma unroll
      for (int a = 0; a < NT; ++a) {
        const int t = a * 16 + lc;
        const int byte = t * 256 + (((kk * 32 + g * 8) * 2) ^ ((t & 7) << 4) ^ ((t & 8) << 1));
        a2[a] = *reinterpret_cast<const short8*>(&lH[byte >> 1]);
      }
#pragma unroll
      for (int a = 0; a < NT; ++a)
#pragma unroll
        for (int nn = 0; nn < 2; ++nn)
          acc_out[a][nn] = __builtin_amdgcn_mfma_f32_16x16x32_bf16(a2[a], b2p[kk][nn], acc_out[a][nn], 0, 0, 0);
    }
    // next chunk's nonlin writes the OTHER lH buffer -> no second barrier.
  }

  // ---- epilogue: scatter acc to LDS fp32 (exactly T*256 floats), flat copy ----
  __syncthreads();                       // all GEMM2(7) lH reads done
  float* ldsF = reinterpret_cast<float*>(lds);
  constexpr int RW = 256 * OUT_M;        // floats per output row
  if constexpr (OUT_M == 1) {
#pragma unroll
    for (int a = 0; a < NT; ++a)
#pragma unroll
      for (int nn = 0; nn < 2; ++nn) {
        const int d = wave * 32 + nn * 16 + lc;
#pragma unroll
        for (int reg = 0; reg < 4; ++reg) {
          const int t = a * 16 + g * 4 + reg;
          ldsF[t * RW + d] = acc_out[a][nn][reg];
        }
      }
  } else {
#pragma unroll
    for (int mm = 0; mm < NT; ++mm)
#pragma unroll
      for (int nn = 0; nn < 2; ++nn) {
        const int d = wave * 32 + nn * 16 + lc;
#pragma unroll
        for (int reg = 0; reg < 4; ++reg) {
          const int r = g * 4 + reg;
          ldsF[r * RW + d * OUT_M + mm] = acc_out[mm][nn][reg];
        }
      }
  }
  __syncthreads();
  // block tile is contiguous in out: rows [row0, row0+R) -> R*RW floats
  float* obase = out + row0 * RW;
  constexpr int NF4 = (R * RW) / 4;
  for (int i = tid; i < NF4; i += 512) {
    const f32x4 v = *reinterpret_cast<const f32x4*>(&ldsF[i * 4]);
    __builtin_nontemporal_store(v, reinterpret_cast<f32x4*>(obase) + i);
  }
}

extern "C" void kernel_launch(void* const* d_in, const int* in_sizes, int n_in,
                              void* d_out, int out_size, void* d_ws, size_t ws_size,
                              hipStream_t stream)
{
  // d_in order per setup_inputs: (x, w_in, scale, bias, w_out) x degree 0..2
  short* ws = (short*)d_ws;                 // 6 * 512KB = 3MB
  const size_t WSZ = 262144;                // shorts per packed matrix
  float* outf = (float*)d_out;
  const size_t out_off[3] = {0, 4194304, 16777216};  // y0|y1|y2 concat (m=1,3,5)

  pack_all_k<<<768, 256, 0, stream>>>(
      (const float*)d_in[1],  (const float*)d_in[4],
      (const float*)d_in[6],  (const float*)d_in[9],
      (const float*)d_in[11], (const float*)d_in[14], ws);

  // deg0 (m=1): 32 rows/block; LDS 32 KB
  ff_se3_kernel<2, 1, 1><<<512, 512, 32768, stream>>>(
      (const float*)d_in[0], ws + 0 * WSZ, ws + 1 * WSZ,
      (const float*)d_in[2], (const float*)d_in[3], outf + out_off[0]);

  // deg1 (m=3): LDS 48 KB
  ff_se3_kernel<3, 3, 3><<<1024, 512, 49152, stream>>>(
      (const float*)d_in[5], ws + 2 * WSZ, ws + 3 * WSZ,
      (const float*)d_in[7], (const float*)d_in[8], outf + out_off[1]);

  // deg2 (m=5): LDS 80 KB (2 blocks/CU, 16 waves/CU)
  ff_se3_kernel<5, 5, 5><<<1024, 512, 81920, stream>>>(
      (const float*)d_in[10], ws + 4 * WSZ, ws + 5 * WSZ,
      (const float*)d_in[12], (const float*)d_in[13], outf + out_off[2]);
}

// Round 14
// 266.896 us; speedup vs baseline: 1.2883x; 1.2883x over previous
//
#include <hip/hip_runtime.h>
#include <hip/hip_bf16.h>

// Fused SE(3) feedforward, bf16 MFMA, fp32 accumulate.
// Round 14: R7 base (best, 232us) + G1 B-frag full preload (bfr8[8] before
// kt-loop, mirrors proven G2 b2p pattern) + b2p issued before G1 (deeper
// in-flight window) + M=1 direct-x (no staging/lA, R10/R12-proven).
// No structural/barrier changes vs R7.

typedef __attribute__((ext_vector_type(8))) short short8;   // 8 bf16 (MFMA A/B frag)
typedef __attribute__((ext_vector_type(4))) float f32x4;    // MFMA C/D frag

static __device__ __forceinline__ short f2bf(float f) {
  __hip_bfloat16 h = __float2bfloat16(f);
  return *reinterpret_cast<short*>(&h);
}

// ---- fused weight packing into MFMA-fragment order (bf16) ----
// region r = blockIdx.x>>7: r=2*dg+0 -> w_in(dg), r=2*dg+1 -> w_out(dg).
__global__ void pack_all_k(const float* __restrict__ w0i, const float* __restrict__ w0o,
                           const float* __restrict__ w1i, const float* __restrict__ w1o,
                           const float* __restrict__ w2i, const float* __restrict__ w2o,
                           short* __restrict__ p) {
  const int region = blockIdx.x >> 7;                 // 0..5
  const int gid = (blockIdx.x & 127) * 256 + threadIdx.x;  // 0..32767
  const int lane = gid & 63;
  const int tile = gid >> 6;
  const int gg = lane >> 4, cc = lane & 15;
  const float* w = (region == 0) ? w0i : (region == 1) ? w0o :
                   (region == 2) ? w1i : (region == 3) ? w1o :
                   (region == 4) ? w2i : w2o;
  short8 v;
  if (region & 1) {   // w_out pack: tile (kt2<32, nt2<16)
    const int nt2 = tile & 15, kt2 = tile >> 4;
#pragma unroll
    for (int j = 0; j < 8; ++j)
      v[j] = f2bf(w[(kt2 * 32 + gg * 8 + j) * 256 + nt2 * 16 + cc]);
  } else {            // w_in pack: tile (nt<64, kt<8)
    const int kt = tile & 7, nt = tile >> 3;
#pragma unroll
    for (int j = 0; j < 8; ++j)
      v[j] = f2bf(w[(kt * 32 + gg * 8 + j) * 1024 + nt * 16 + cc]);
  }
  *reinterpret_cast<short8*>(p + ((size_t)region * 262144) + gid * 8) = v;
}

// ---- fused main kernel (8 waves) ----
// NT token tiles of 16; tokens t = a*16 + r. GRP = norm-group size over tiles
// (GRP==NT for deg>0 where a=mm; GRP==1 for deg0 at 32 rows).
// MODE: 0 = lA LDS staging, 2 = direct-x A-frags (M=1 only, d contiguous).
// LDS XOR swizzle: byte ^= (t&7)<<4.
template<int NT, int GRP, int OUT_M, int MODE>
__global__ __launch_bounds__(512, 4)
void ff_se3_kernel(const float* __restrict__ x,
                   const short* __restrict__ wpin,
                   const short* __restrict__ wpout,
                   const float* __restrict__ scale,
                   const float* __restrict__ bias,
                   float* __restrict__ out)
{
  constexpr int T = 16 * NT;                  // tokens per block
  constexpr int R = (OUT_M == 1) ? T : 16;    // output rows per block
  extern __shared__ short lds[];              // MODE0: T*512(lA)+2*T*256(lH); MODE2: lH only
  short* lA  = lds;
  short* lH0 = (MODE == 0) ? (lds + T * 256) : lds;
  short* lH1 = lH0 + T * 128;

  const int tid  = threadIdx.x;
  const int lane = tid & 63;
  const int wave = tid >> 6;                  // 0..7
  const int g    = lane >> 4;
  const int lc   = lane & 15;
  const long row0 = (long)blockIdx.x * R;

  if constexpr (MODE == 0) {
    // stage x -> lA (nt float4 reads, scatter bf16 into token layout)
    for (int e4 = tid; e4 < R * 64 * OUT_M; e4 += 512) {
      const int r  = e4 / (64 * OUT_M);
      const int o4 = e4 - r * (64 * OUT_M);
      const f32x4 v = __builtin_nontemporal_load(
          reinterpret_cast<const f32x4*>(x + (row0 + r) * (256 * OUT_M) + o4 * 4));
#pragma unroll
      for (int i = 0; i < 4; ++i) {
        const int flat = o4 * 4 + i;
        const int d  = flat / OUT_M;
        const int mm = flat - d * OUT_M;
        const int t  = mm * 16 + r;
        const int byte = t * 512 + ((d * 2) ^ ((t & 7) << 4));
        lA[byte >> 1] = f2bf(v[i]);
      }
    }
  }

  f32x4 acc_out[NT][2];                       // wave owns 32 d-cols (2 n-tiles)
#pragma unroll
  for (int a = 0; a < NT; ++a) { acc_out[a][0] = (f32x4)(0.f); acc_out[a][1] = (f32x4)(0.f); }

  if constexpr (MODE == 0) __syncthreads();

  for (int c = 0; c < 8; ++c) {   // 128-h chunks
    short* lH = (c & 1) ? lH1 : lH0;

    // scale/bias prefetch (hidden under G1); wave owns cols [wave*16, +16)
    const int hgl = c * 128 + wave * 16 + lc;
    const float sc = scale[hgl];
    const float bi = bias[hgl];

    // ---- preload ALL G1 B-frags for this chunk (8 x 1KB, L2-resident) ----
    const int ntg = c * 8 + wave;
    short8 bfr8[8];
#pragma unroll
    for (int kt = 0; kt < 8; ++kt)
      bfr8[kt] = *reinterpret_cast<const short8*>(wpin + ((ntg * 8 + kt) * 64 + lane) * 8);

    // ---- preload G2 B-frags (in flight across G1 + nonlin + barrier) ----
    short8 b2p[4][2];
#pragma unroll
    for (int kk = 0; kk < 4; ++kk)
#pragma unroll
      for (int nn = 0; nn < 2; ++nn) {
        const int tile = (c * 4 + kk) * 16 + wave * 2 + nn;
        b2p[kk][nn] = *reinterpret_cast<const short8*>(wpout + (tile * 64 + lane) * 8);
      }

    // ---- GEMM1: wave owns 16 h-cols (1 n-tile), K=256 ----
    f32x4 acc1[NT];
#pragma unroll
    for (int a = 0; a < NT; ++a) acc1[a] = (f32x4)(0.f);
#pragma unroll
    for (int kt = 0; kt < 8; ++kt) {
      short8 af[NT];
#pragma unroll
      for (int a = 0; a < NT; ++a) {
        if constexpr (MODE == 0) {
          const int t = a * 16 + lc;
          const int byte = t * 512 + (((kt * 32 + g * 8) * 2) ^ ((t & 7) << 4));
          af[a] = *reinterpret_cast<const short8*>(&lA[byte >> 1]);
        } else {  // MODE 2: direct from x (OUT_M==1), 32 KB/block slab, L1/L2-hot
          const float* xp = x + ((row0 + a * 16 + lc) * 256 + kt * 32 + g * 8);
          const f32x4 p0 = *reinterpret_cast<const f32x4*>(xp);
          const f32x4 p1 = *reinterpret_cast<const f32x4*>(xp + 4);
          short8 t8;
#pragma unroll
          for (int j = 0; j < 4; ++j) { t8[j] = f2bf(p0[j]); t8[4 + j] = f2bf(p1[j]); }
          af[a] = t8;
        }
      }
#pragma unroll
      for (int a = 0; a < NT; ++a)
        acc1[a] = __builtin_amdgcn_mfma_f32_16x16x32_bf16(af[a], bfr8[kt], acc1[a], 0, 0, 0);
    }

    // ---- nonlinearity: per-(row,h) norm over its GRP tiles + gelu gate ----
#pragma unroll
    for (int reg = 0; reg < 4; ++reg) {
#pragma unroll
      for (int gi = 0; gi < NT / GRP; ++gi) {
        float ns = 0.f;
#pragma unroll
        for (int k = 0; k < GRP; ++k) {
          const float h = acc1[gi * GRP + k][reg];
          ns += h * h;
        }
        ns = fmaxf(ns, 1e-24f);
        const float rn  = __builtin_amdgcn_rsqf(ns);
        const float nrm = ns * rn;
        const float z   = fmaf(nrm, sc, bi);
        float u2 = 2.f * z * fmaf(0.0356774081f * z, z, 0.7978845608f);
        u2 = fminf(u2, 30.f);
        const float e  = __expf(u2);
        const float th = (e - 1.f) * __builtin_amdgcn_rcpf(e + 1.f);
        const float fac = 0.5f * (1.f + th) * z * rn;
        const int tl  = g * 4 + reg;
        const int col = wave * 16 + lc;
#pragma unroll
        for (int k = 0; k < GRP; ++k) {
          const int a = gi * GRP + k;
          const int t = a * 16 + tl;
          const int byte = t * 256 + ((col * 2) ^ ((t & 7) << 4));
          lH[byte >> 1] = f2bf(acc1[a][reg] * fac);
        }
      }
    }

    __syncthreads();   // the ONLY barrier per chunk

    // ---- GEMM2 partial: wave owns d-cols [wave*32, +32) ----
#pragma unroll
    for (int kk = 0; kk < 4; ++kk) {
      short8 a2[NT];
#pragma unroll
      for (int a = 0; a < NT; ++a) {
        const int t = a * 16 + lc;
        const int byte = t * 256 + (((kk * 32 + g * 8) * 2) ^ ((t & 7) << 4));
        a2[a] = *reinterpret_cast<const short8*>(&lH[byte >> 1]);
      }
#pragma unroll
      for (int a = 0; a < NT; ++a)
#pragma unroll
        for (int nn = 0; nn < 2; ++nn)
          acc_out[a][nn] = __builtin_amdgcn_mfma_f32_16x16x32_bf16(a2[a], b2p[kk][nn], acc_out[a][nn], 0, 0, 0);
    }
    // next chunk's nonlin writes the OTHER lH buffer -> no second barrier.
  }

  // ---- epilogue: scatter acc to LDS fp32 (exactly T*256 floats), flat copy ----
  __syncthreads();                       // all GEMM2(7) lH reads done
  float* ldsF = reinterpret_cast<float*>(lds);
  constexpr int RW = 256 * OUT_M;        // floats per output row
  if constexpr (OUT_M == 1) {
#pragma unroll
    for (int a = 0; a < NT; ++a)
#pragma unroll
      for (int nn = 0; nn < 2; ++nn) {
        const int d = wave * 32 + nn * 16 + lc;
#pragma unroll
        for (int reg = 0; reg < 4; ++reg) {
          const int t = a * 16 + g * 4 + reg;
          ldsF[t * RW + d] = acc_out[a][nn][reg];
        }
      }
  } else {
#pragma unroll
    for (int mm = 0; mm < NT; ++mm)
#pragma unroll
      for (int nn = 0; nn < 2; ++nn) {
        const int d = wave * 32 + nn * 16 + lc;
#pragma unroll
        for (int reg = 0; reg < 4; ++reg) {
          const int r = g * 4 + reg;
          ldsF[r * RW + d * OUT_M + mm] = acc_out[mm][nn][reg];
        }
      }
  }
  __syncthreads();
  // block tile is contiguous in out: rows [row0, row0+R) -> R*RW floats
  float* obase = out + row0 * RW;
  constexpr int NF4 = (R * RW) / 4;
  for (int i = tid; i < NF4; i += 512) {
    const f32x4 v = *reinterpret_cast<const f32x4*>(&ldsF[i * 4]);
    __builtin_nontemporal_store(v, reinterpret_cast<f32x4*>(obase) + i);
  }
}

extern "C" void kernel_launch(void* const* d_in, const int* in_sizes, int n_in,
                              void* d_out, int out_size, void* d_ws, size_t ws_size,
                              hipStream_t stream)
{
  // d_in order per setup_inputs: (x, w_in, scale, bias, w_out) x degree 0..2
  short* ws = (short*)d_ws;                 // 6 * 512KB = 3MB
  const size_t WSZ = 262144;                // shorts per packed matrix
  float* outf = (float*)d_out;
  const size_t out_off[3] = {0, 4194304, 16777216};  // y0|y1|y2 concat (m=1,3,5)

  pack_all_k<<<768, 256, 0, stream>>>(
      (const float*)d_in[1],  (const float*)d_in[4],
      (const float*)d_in[6],  (const float*)d_in[9],
      (const float*)d_in[11], (const float*)d_in[14], ws);

  // deg0 (m=1): direct-x, 32 rows/block; LDS 32 KB (epilogue overlay)
  ff_se3_kernel<2, 1, 1, 2><<<512, 512, 32768, stream>>>(
      (const float*)d_in[0], ws + 0 * WSZ, ws + 1 * WSZ,
      (const float*)d_in[2], (const float*)d_in[3], outf + out_off[0]);

  // deg1 (m=3): LDS 48 KB
  ff_se3_kernel<3, 3, 3, 0><<<1024, 512, 49152, stream>>>(
      (const float*)d_in[5], ws + 2 * WSZ, ws + 3 * WSZ,
      (const float*)d_in[7], (const float*)d_in[8], outf + out_off[1]);

  // deg2 (m=5): LDS 80 KB (2 blocks/CU, 16 waves/CU)
  ff_se3_kernel<5, 5, 5, 0><<<1024, 512, 81920, stream>>>(
      (const float*)d_in[10], ws + 4 * WSZ, ws + 5 * WSZ,
      (const float*)d_in[12], (const float*)d_in[13], outf + out_off[2]);
}